// Round 3
// baseline (812.701 us; speedup 1.0000x reference)
//
#include <hip/hip_runtime.h>

#define NROWS 262144
#define KC 256
#define DD 256
#define BM 128
#define DK 32
#define LSTR 34      // LDS row stride (floats)
#define TAU 2e-4f    // flag threshold: covers fp32 quantization (3e-5) + A/B rounding (6.2e-5)

// ===== bit-exact numpy emulation helpers (defeat -ffp-contract) =====
// numpy pairwise_sum of 128 elements a[i]^2 (squares rounded individually):
// 8 accumulators, then ((r0+r1)+(r2+r3)) + ((r4+r5)+(r6+r7))
__device__ __forceinline__ float np_pw128_sq(const float* a) {
    float r[8];
#pragma unroll
    for (int j = 0; j < 8; ++j) r[j] = __fmul_rn(a[j], a[j]);
    for (int i = 8; i < 128; i += 8) {
#pragma unroll
        for (int j = 0; j < 8; ++j)
            r[j] = __fadd_rn(r[j], __fmul_rn(a[i + j], a[i + j]));
    }
    float t01 = __fadd_rn(r[0], r[1]), t23 = __fadd_rn(r[2], r[3]);
    float t45 = __fadd_rn(r[4], r[5]), t67 = __fadd_rn(r[6], r[7]);
    return __fadd_rn(__fadd_rn(t01, t23), __fadd_rn(t45, t67));
}
// np.sum(x**2) for n=256: pairwise splits into two 128-blocks
__device__ __forceinline__ float np_sum256_sq(const float* a) {
    return __fadd_rn(np_pw128_sq(a), np_pw128_sq(a + 128));
}

// ---------- prep: se[k] = np-bit-exact sum(emb[k]^2), zero loss accumulator ----------
__global__ void vq_prep(const float* __restrict__ emb, float* __restrict__ se,
                        double* __restrict__ accum) {
    int k = threadIdx.x;
    if (k == 0) *accum = 0.0;
    se[k] = np_sum256_sq(emb + (size_t)k * DD);
}

// ---------- main: per-block 128 rows x 256 codes ----------
__global__ __launch_bounds__(256, 2)
void vq_main(const float* __restrict__ ze, const float* __restrict__ emb,
             const float* __restrict__ se_g, float* __restrict__ out_zq,
             float* __restrict__ out_inds, double* __restrict__ accum)
{
    __shared__ float  zs[BM][LSTR];
    __shared__ float  es[KC][LSTR];
    __shared__ float  se_s[KC];
    __shared__ int    inds_s[BM];
    __shared__ int    flist[BM];
    __shared__ int    nflag;
    __shared__ float  red[256];
    __shared__ int    rk2[256];
    __shared__ float  zfull[256];
    __shared__ float  srow;

    const int t  = threadIdx.x;
    const int tk = t & 15;   // code group: k = tk + 16*ki
    const int tm = t >> 4;   // row group: m = tm*8 + mi
    const size_t m0 = (size_t)blockIdx.x * BM;

    se_s[t] = se_g[t];
    if (t == 0) nflag = 0;

    float acc[8][16];
#pragma unroll
    for (int i = 0; i < 8; ++i)
#pragma unroll
        for (int j = 0; j < 16; ++j) acc[i][j] = 0.f;
    float sz_acc = 0.f;

    for (int dc = 0; dc < DD; dc += DK) {
        __syncthreads();
#pragma unroll
        for (int it = 0; it < 4; ++it) {
            int idx = it * 256 + t;
            int row = idx >> 3, c4 = idx & 7;
            float4 v = *reinterpret_cast<const float4*>(ze + (m0 + row) * DD + dc + c4 * 4);
            sz_acc = fmaf(v.x, v.x, sz_acc); sz_acc = fmaf(v.y, v.y, sz_acc);
            sz_acc = fmaf(v.z, v.z, sz_acc); sz_acc = fmaf(v.w, v.w, sz_acc);
            float* p = &zs[row][c4 * 4];
            p[0] = v.x; p[1] = v.y; p[2] = v.z; p[3] = v.w;
        }
#pragma unroll
        for (int it = 0; it < 8; ++it) {
            int idx = it * 256 + t;
            int row = idx >> 3, c4 = idx & 7;
            float4 v = *reinterpret_cast<const float4*>(emb + (size_t)row * DD + dc + c4 * 4);
            float* p = &es[row][c4 * 4];
            p[0] = v.x; p[1] = v.y; p[2] = v.z; p[3] = v.w;
        }
        __syncthreads();
#pragma unroll 4
        for (int d = 0; d < DK; ++d) {
            float zr[8], er[16];
#pragma unroll
            for (int mi = 0; mi < 8; ++mi) zr[mi] = zs[tm * 8 + mi][d];
#pragma unroll
            for (int ki = 0; ki < 16; ++ki) er[ki] = es[tk + 16 * ki][d];
#pragma unroll
            for (int mi = 0; mi < 8; ++mi)
#pragma unroll
                for (int ki = 0; ki < 16; ++ki)
                    acc[mi][ki] = fmaf(zr[mi], er[ki], acc[mi][ki]);
        }
    }
    __syncthreads();

    // ---- per-row argmin of dist' = se[k] - 2*dot (fp32), second-min tracked ----
    float lossv = 0.f;
#pragma unroll
    for (int mi = 0; mi < 8; ++mi) {
        float v1 = 3.4e38f, v2 = 3.4e38f; int k1 = 0x7fffffff;
#pragma unroll
        for (int ki = 0; ki < 16; ++ki) {
            int k = tk + 16 * ki;
            float dv = fmaf(-2.f, acc[mi][ki], se_s[k]);
            if (dv < v1) { v2 = v1; v1 = dv; k1 = k; }
            else if (dv < v2) { v2 = dv; }
        }
#pragma unroll
        for (int off = 1; off < 16; off <<= 1) {
            float ov1 = __shfl_xor(v1, off, 64);
            float ov2 = __shfl_xor(v2, off, 64);
            int   ok1 = __shfl_xor(k1, off, 64);
            bool other = (ov1 < v1) || (ov1 == v1 && ok1 < k1);
            float nv2 = other ? fminf(v1, ov2) : fminf(v2, ov1);
            if (other) { v1 = ov1; k1 = ok1; }
            v2 = nv2;
        }
        if (tk == 0) {
            int row = tm * 8 + mi;
            inds_s[row] = k1;
            lossv += v1;
            if (v2 - v1 < TAU) {
                int s = atomicAdd(&nflag, 1);
                flist[s] = row;
            }
        }
    }
    __syncthreads();

    // ---- flagged rows: BIT-EXACT numpy fp32 pipeline emulation ----
    // Dq[k] = fl32( fl32(sz_np + se_np[k]) - 2 * seqFMA32(dot) ), argmin first-occurrence.
    int nf = nflag;
    for (int f = 0; f < nf; ++f) {
        int row = flist[f];
        if (t < 64)
            reinterpret_cast<float4*>(zfull)[t] =
                reinterpret_cast<const float4*>(ze + (m0 + row) * DD)[t];
        __syncthreads();
        if (t == 0) srow = np_sum256_sq(zfull);   // np pairwise ||z||^2 (any fp32 works; exact anyway)
        __syncthreads();
        // thread t emulates code k=t: sequential single-accumulator FMA over d (BLAS microkernel order)
        const float4* e4p = reinterpret_cast<const float4*>(emb + (size_t)t * DD);
        float m32 = 0.f;
        for (int d4 = 0; d4 < 64; ++d4) {
            float4 e4 = e4p[d4];
            int d = d4 * 4;
            m32 = __fmaf_rn(zfull[d + 0], e4.x, m32);
            m32 = __fmaf_rn(zfull[d + 1], e4.y, m32);
            m32 = __fmaf_rn(zfull[d + 2], e4.z, m32);
            m32 = __fmaf_rn(zfull[d + 3], e4.w, m32);
        }
        float A  = __fadd_rn(srow, se_s[t]);             // fl32(sz + se[k])
        float Dq = __fsub_rn(A, __fmul_rn(2.0f, m32));   // fl32(A - 2*M32)
        red[t] = Dq; rk2[t] = t;
        __syncthreads();
        for (int s = 128; s > 0; s >>= 1) {
            if (t < s) {
                float vo = red[t + s]; int ko = rk2[t + s];
                if (vo < red[t] || (vo == red[t] && ko < rk2[t])) { red[t] = vo; rk2[t] = ko; }
            }
            __syncthreads();
        }
        if (t == 0) inds_s[row] = rk2[0];
        __syncthreads();
    }

    // ---- write indices (as float) ----
    if (t < BM) out_inds[m0 + t] = (float)inds_s[t];

    // ---- gather + write z_q ----
    const int w = t >> 6, l = t & 63;
    for (int r = w; r < BM; r += 4) {
        int k = inds_s[r];
        float4 v = *reinterpret_cast<const float4*>(emb + (size_t)k * DD + l * 4);
        *reinterpret_cast<float4*>(out_zq + (m0 + r) * DD + l * 4) = v;
    }

    // ---- loss partial ----
    red[t] = sz_acc + lossv;
    __syncthreads();
    for (int s = 128; s > 0; s >>= 1) {
        if (t < s) red[t] += red[t + s];
        __syncthreads();
    }
    if (t == 0) atomicAdd(accum, (double)red[0]);
}

// ---------- finalize: loss = (1 + 0.25) * mean((z - q)^2) ----------
__global__ void vq_fin(const double* __restrict__ accum, float* __restrict__ out_loss) {
    *out_loss = (float)(1.25 * (*accum) / ((double)NROWS * (double)DD));
}

extern "C" void kernel_launch(void* const* d_in, const int* in_sizes, int n_in,
                              void* d_out, int out_size, void* d_ws, size_t ws_size,
                              hipStream_t stream) {
    const float* ze  = (const float*)d_in[0];
    const float* emb = (const float*)d_in[1];
    float* out      = (float*)d_out;
    float* out_zq   = out;
    float* out_inds = out + (size_t)NROWS * DD;
    float* out_loss = out + (size_t)NROWS * DD + NROWS;
    double* accum = (double*)d_ws;
    float*  se    = (float*)((char*)d_ws + 16);

    vq_prep<<<1, 256, 0, stream>>>(emb, se, accum);
    vq_main<<<NROWS / BM, 256, 0, stream>>>(ze, emb, se, out_zq, out_inds, accum);
    vq_fin<<<1, 1, 0, stream>>>(accum, out_loss);
}

// Round 5
// 407.921 us; speedup vs baseline: 1.9923x; 1.9923x over previous
//
#include <hip/hip_runtime.h>

typedef __attribute__((ext_vector_type(8))) short bf16x8;
typedef __attribute__((ext_vector_type(4))) float f32x4;
typedef __attribute__((ext_vector_type(4))) unsigned short us4;
typedef __attribute__((ext_vector_type(8))) unsigned short us8;

#define NROWS 262144
#define KC 256
#define DD 256
#define BM 64        // rows per block
#define DK 32        // D-chunk (= one MFMA K)
#define SW 40        // LDS k-stride in bf16 (32 + 8 pad -> 80B rows, uniform banks)
#define TAU 3e-4f    // flag threshold: covers np fp32 rounding (6.2e-5) + bf16-split err (3.2e-5), 3x margin

// ===== bit-exact numpy emulation helpers (defeat -ffp-contract) =====
__device__ __forceinline__ float np_pw128_sq(const float* a) {
    float r[8];
#pragma unroll
    for (int j = 0; j < 8; ++j) r[j] = __fmul_rn(a[j], a[j]);
    for (int i = 8; i < 128; i += 8) {
#pragma unroll
        for (int j = 0; j < 8; ++j)
            r[j] = __fadd_rn(r[j], __fmul_rn(a[i + j], a[i + j]));
    }
    float t01 = __fadd_rn(r[0], r[1]), t23 = __fadd_rn(r[2], r[3]);
    float t45 = __fadd_rn(r[4], r[5]), t67 = __fadd_rn(r[6], r[7]);
    return __fadd_rn(__fadd_rn(t01, t23), __fadd_rn(t45, t67));
}
__device__ __forceinline__ float np_sum256_sq(const float* a) {
    return __fadd_rn(np_pw128_sq(a), np_pw128_sq(a + 128));
}

// split fp32 x = hi + lo (bf16 each): hi = truncate, lo = RNE(x - hi); residual <= 2^-17|x|
// returns (hi << 16) | lo
__device__ __forceinline__ unsigned cvt_split(float x) {
    unsigned b = __float_as_uint(x);
    unsigned hi = b >> 16;
    float hif = __uint_as_float(b & 0xFFFF0000u);
    float r = x - hif;
    unsigned rb = __float_as_uint(r);
    rb += 0x7FFFu + ((rb >> 16) & 1u);
    return (hi << 16) | (rb >> 16);
}

// ---------- prep: se[k] = np-bit-exact sum(emb[k]^2), zero loss accumulator ----------
__global__ void vq_prep(const float* __restrict__ emb, float* __restrict__ se,
                        double* __restrict__ accum) {
    int k = threadIdx.x;
    if (k == 0) *accum = 0.0;
    se[k] = np_sum256_sq(emb + (size_t)k * DD);
}

// ---------- main: per-block 64 rows x 256 codes, bf16-split MFMA ----------
__global__ __launch_bounds__(256, 2)
void vq_main(const float* __restrict__ ze, const float* __restrict__ emb,
             const float* __restrict__ se_g, float* __restrict__ out_zq,
             float* __restrict__ out_inds, double* __restrict__ accum)
{
    __shared__ __attribute__((aligned(16))) unsigned short zs_hi[BM * SW];
    __shared__ __attribute__((aligned(16))) unsigned short zs_lo[BM * SW];
    __shared__ __attribute__((aligned(16))) unsigned short es_hi[KC * SW];
    __shared__ __attribute__((aligned(16))) unsigned short es_lo[KC * SW];
    __shared__ float  se_s[KC];
    __shared__ float  wv1[4 * BM], wv2[4 * BM];
    __shared__ int    wk1[4 * BM];
    __shared__ int    inds_s[BM];
    __shared__ int    flist[BM];
    __shared__ int    nflag;
    __shared__ float  red[256];
    __shared__ int    rk2[256];
    __shared__ float  zfull[256];
    __shared__ float  srow;

    const int t = threadIdx.x;
    const int w = t >> 6;          // wave: cols [64w, 64w+64)
    const int l = t & 63;
    const int q = (t >> 4) & 3;    // lane quad
    const int c = t & 15;
    const size_t m0 = (size_t)blockIdx.x * BM;

    se_s[t] = se_g[t];
    if (t == 0) nflag = 0;

    f32x4 acc[4][4];
#pragma unroll
    for (int i = 0; i < 4; ++i)
#pragma unroll
        for (int j = 0; j < 4; ++j) acc[i][j] = (f32x4){0.f, 0.f, 0.f, 0.f};
    float sz_acc = 0.f;

    for (int dc = 0; dc < DD; dc += DK) {
        __syncthreads();
        // ---- stage z tile: 64 rows x 32 d, fp32 -> bf16 hi/lo ----
#pragma unroll
        for (int it = 0; it < 2; ++it) {
            int idx = it * 256 + t;
            int row = idx >> 3, c4 = idx & 7;
            float4 v = *reinterpret_cast<const float4*>(ze + (m0 + row) * DD + dc + c4 * 4);
            sz_acc = fmaf(v.x, v.x, sz_acc); sz_acc = fmaf(v.y, v.y, sz_acc);
            sz_acc = fmaf(v.z, v.z, sz_acc); sz_acc = fmaf(v.w, v.w, sz_acc);
            unsigned p0 = cvt_split(v.x), p1 = cvt_split(v.y);
            unsigned p2 = cvt_split(v.z), p3 = cvt_split(v.w);
            us4 h, lo;
            h[0] = (unsigned short)(p0 >> 16); lo[0] = (unsigned short)p0;
            h[1] = (unsigned short)(p1 >> 16); lo[1] = (unsigned short)p1;
            h[2] = (unsigned short)(p2 >> 16); lo[2] = (unsigned short)p2;
            h[3] = (unsigned short)(p3 >> 16); lo[3] = (unsigned short)p3;
            *reinterpret_cast<us4*>(&zs_hi[row * SW + c4 * 4]) = h;
            *reinterpret_cast<us4*>(&zs_lo[row * SW + c4 * 4]) = lo;
        }
        // ---- stage e tile: 256 codes x 32 d, fp32 -> bf16 hi/lo ----
#pragma unroll
        for (int it = 0; it < 4; ++it) {
            int idx = it * 256 + t;
            int row = idx >> 2, c8 = idx & 3;
            const float4* g = reinterpret_cast<const float4*>(emb + (size_t)row * DD + dc + c8 * 8);
            float4 va = g[0], vb = g[1];
            unsigned p[8];
            p[0] = cvt_split(va.x); p[1] = cvt_split(va.y);
            p[2] = cvt_split(va.z); p[3] = cvt_split(va.w);
            p[4] = cvt_split(vb.x); p[5] = cvt_split(vb.y);
            p[6] = cvt_split(vb.z); p[7] = cvt_split(vb.w);
            us8 h, lo;
#pragma unroll
            for (int j = 0; j < 8; ++j) {
                h[j] = (unsigned short)(p[j] >> 16);
                lo[j] = (unsigned short)p[j];
            }
            *reinterpret_cast<us8*>(&es_hi[row * SW + c8 * 8]) = h;
            *reinterpret_cast<us8*>(&es_lo[row * SW + c8 * 8]) = lo;
        }
        __syncthreads();
        // ---- MFMA: wave tile 64 rows x 64 cols, 4x4 frags, 3 passes ----
        bf16x8 a_hi[4], a_lo[4], b_hi[4], b_lo[4];
#pragma unroll
        for (int mf = 0; mf < 4; ++mf) {
            a_hi[mf] = *reinterpret_cast<const bf16x8*>(&zs_hi[(16 * mf + c) * SW + q * 8]);
            a_lo[mf] = *reinterpret_cast<const bf16x8*>(&zs_lo[(16 * mf + c) * SW + q * 8]);
        }
#pragma unroll
        for (int nf = 0; nf < 4; ++nf) {
            b_hi[nf] = *reinterpret_cast<const bf16x8*>(&es_hi[(64 * w + 16 * nf + c) * SW + q * 8]);
            b_lo[nf] = *reinterpret_cast<const bf16x8*>(&es_lo[(64 * w + 16 * nf + c) * SW + q * 8]);
        }
#pragma unroll
        for (int mf = 0; mf < 4; ++mf)
#pragma unroll
            for (int nf = 0; nf < 4; ++nf) {
                acc[mf][nf] = __builtin_amdgcn_mfma_f32_16x16x32_bf16(a_lo[mf], b_hi[nf], acc[mf][nf], 0, 0, 0);
                acc[mf][nf] = __builtin_amdgcn_mfma_f32_16x16x32_bf16(a_hi[mf], b_lo[nf], acc[mf][nf], 0, 0, 0);
                acc[mf][nf] = __builtin_amdgcn_mfma_f32_16x16x32_bf16(a_hi[mf], b_hi[nf], acc[mf][nf], 0, 0, 0);
            }
    }

    // ---- per-row argmin over this wave's 64-col slice (v1, v2, k1) ----
#pragma unroll
    for (int mf = 0; mf < 4; ++mf)
#pragma unroll
        for (int j = 0; j < 4; ++j) {
            float v1 = 3.4e38f, v2 = 3.4e38f; int k1 = 0x7fffffff;
#pragma unroll
            for (int nf = 0; nf < 4; ++nf) {
                int k = 64 * w + 16 * nf + c;
                float dv = fmaf(-2.f, acc[mf][nf][j], se_s[k]);
                if (dv < v1) { v2 = v1; v1 = dv; k1 = k; }
                else if (dv < v2) { v2 = dv; }
            }
#pragma unroll
            for (int off = 1; off < 16; off <<= 1) {
                float ov1 = __shfl_xor(v1, off, 64);
                float ov2 = __shfl_xor(v2, off, 64);
                int   ok1 = __shfl_xor(k1, off, 64);
                bool other = (ov1 < v1) || (ov1 == v1 && ok1 < k1);
                float nv2 = other ? fminf(v1, ov2) : fminf(v2, ov1);
                if (other) { v1 = ov1; k1 = ok1; }
                v2 = nv2;
            }
            if (c == 0) {
                int row = 16 * mf + 4 * q + j;
                wv1[w * BM + row] = v1; wv2[w * BM + row] = v2; wk1[w * BM + row] = k1;
            }
        }
    __syncthreads();

    // ---- cross-wave merge (t < 64: one row each), flag near-ties ----
    float lossv = 0.f;
    if (t < BM) {
        float v1 = wv1[t], v2 = wv2[t]; int k1 = wk1[t];
#pragma unroll
        for (int ww = 1; ww < 4; ++ww) {
            float ov1 = wv1[ww * BM + t], ov2 = wv2[ww * BM + t];
            int ok1 = wk1[ww * BM + t];
            bool other = (ov1 < v1) || (ov1 == v1 && ok1 < k1);
            float nv2 = other ? fminf(v1, ov2) : fminf(v2, ov1);
            if (other) { v1 = ov1; k1 = ok1; }
            v2 = nv2;
        }
        inds_s[t] = k1;
        lossv = v1;
        if (v2 - v1 < TAU) {
            int s = atomicAdd(&nflag, 1);
            flist[s] = t;
        }
    }
    __syncthreads();

    // ---- flagged rows: BIT-EXACT numpy fp32 pipeline emulation (proven r3) ----
    int nf = nflag;
    for (int f = 0; f < nf; ++f) {
        int row = flist[f];
        if (t < 64)
            reinterpret_cast<float4*>(zfull)[t] =
                reinterpret_cast<const float4*>(ze + (m0 + row) * DD)[t];
        __syncthreads();
        if (t == 0) srow = np_sum256_sq(zfull);
        __syncthreads();
        const float4* e4p = reinterpret_cast<const float4*>(emb + (size_t)t * DD);
        float m32 = 0.f;
        for (int d4 = 0; d4 < 64; ++d4) {
            float4 e4 = e4p[d4];
            int d = d4 * 4;
            m32 = __fmaf_rn(zfull[d + 0], e4.x, m32);
            m32 = __fmaf_rn(zfull[d + 1], e4.y, m32);
            m32 = __fmaf_rn(zfull[d + 2], e4.z, m32);
            m32 = __fmaf_rn(zfull[d + 3], e4.w, m32);
        }
        float A  = __fadd_rn(srow, se_s[t]);
        float Dq = __fsub_rn(A, __fmul_rn(2.0f, m32));
        red[t] = Dq; rk2[t] = t;
        __syncthreads();
        for (int s = 128; s > 0; s >>= 1) {
            if (t < s) {
                float vo = red[t + s]; int ko = rk2[t + s];
                if (vo < red[t] || (vo == red[t] && ko < rk2[t])) { red[t] = vo; rk2[t] = ko; }
            }
            __syncthreads();
        }
        if (t == 0) inds_s[row] = rk2[0];
        __syncthreads();
    }

    // ---- write indices (as float) ----
    if (t < BM) out_inds[m0 + t] = (float)inds_s[t];

    // ---- gather + write z_q (wave per row, lane per float4) ----
    for (int r = w; r < BM; r += 4) {
        int k = inds_s[r];
        float4 v = *reinterpret_cast<const float4*>(emb + (size_t)k * DD + l * 4);
        *reinterpret_cast<float4*>(out_zq + (m0 + r) * DD + l * 4) = v;
    }

    // ---- loss partial ----
    red[t] = sz_acc + lossv;
    __syncthreads();
    for (int s = 128; s > 0; s >>= 1) {
        if (t < s) red[t] += red[t + s];
        __syncthreads();
    }
    if (t == 0) atomicAdd(accum, (double)red[0]);
}

// ---------- finalize: loss = (1 + 0.25) * mean((z - q)^2) ----------
__global__ void vq_fin(const double* __restrict__ accum, float* __restrict__ out_loss) {
    *out_loss = (float)(1.25 * (*accum) / ((double)NROWS * (double)DD));
}

extern "C" void kernel_launch(void* const* d_in, const int* in_sizes, int n_in,
                              void* d_out, int out_size, void* d_ws, size_t ws_size,
                              hipStream_t stream) {
    const float* ze  = (const float*)d_in[0];
    const float* emb = (const float*)d_in[1];
    float* out      = (float*)d_out;
    float* out_zq   = out;
    float* out_inds = out + (size_t)NROWS * DD;
    float* out_loss = out + (size_t)NROWS * DD + NROWS;
    double* accum = (double*)d_ws;
    float*  se    = (float*)((char*)d_ws + 16);

    vq_prep<<<1, 256, 0, stream>>>(emb, se, accum);
    vq_main<<<NROWS / BM, 256, 0, stream>>>(ze, emb, se, out_zq, out_inds, accum);
    vq_fin<<<1, 1, 0, stream>>>(accum, out_loss);
}

// Round 6
// 348.999 us; speedup vs baseline: 2.3287x; 1.1688x over previous
//
#include <hip/hip_runtime.h>

typedef __attribute__((ext_vector_type(8))) short bf16x8;
typedef __attribute__((ext_vector_type(4))) float f32x4;
typedef __attribute__((ext_vector_type(4))) unsigned short us4;
typedef __attribute__((ext_vector_type(8))) unsigned short us8;

#define NROWS 262144
#define KC 256
#define DD 256
#define BM 64        // rows per block
#define DK 32        // D-chunk (= one MFMA K)
#define SW 40        // LDS k-stride in bf16 (80B rows, 16B-aligned, spreads banks)
#define TAU 3e-4f    // flag threshold: covers np fp32 rounding (6.2e-5) + bf16-split err (3.2e-5), 3x margin

// ===== bit-exact numpy emulation helpers (defeat -ffp-contract) =====
__device__ __forceinline__ float np_pw128_sq(const float* a) {
    float r[8];
#pragma unroll
    for (int j = 0; j < 8; ++j) r[j] = __fmul_rn(a[j], a[j]);
    for (int i = 8; i < 128; i += 8) {
#pragma unroll
        for (int j = 0; j < 8; ++j)
            r[j] = __fadd_rn(r[j], __fmul_rn(a[i + j], a[i + j]));
    }
    float t01 = __fadd_rn(r[0], r[1]), t23 = __fadd_rn(r[2], r[3]);
    float t45 = __fadd_rn(r[4], r[5]), t67 = __fadd_rn(r[6], r[7]);
    return __fadd_rn(__fadd_rn(t01, t23), __fadd_rn(t45, t67));
}
__device__ __forceinline__ float np_sum256_sq(const float* a) {
    return __fadd_rn(np_pw128_sq(a), np_pw128_sq(a + 128));
}

// split fp32 x = hi + lo (bf16 each): hi = truncate, lo = RNE(x - hi); returns (hi<<16)|lo
__device__ __forceinline__ unsigned cvt_split(float x) {
    unsigned b = __float_as_uint(x);
    unsigned hi = b >> 16;
    float hif = __uint_as_float(b & 0xFFFF0000u);
    float r = x - hif;
    unsigned rb = __float_as_uint(r);
    rb += 0x7FFFu + ((rb >> 16) & 1u);
    return (hi << 16) | (rb >> 16);
}

// ---------- prep: se[k] = np-bit-exact sum(emb[k]^2), zero loss accumulator ----------
__global__ void vq_prep(const float* __restrict__ emb, float* __restrict__ se,
                        double* __restrict__ accum) {
    int k = threadIdx.x;
    if (k == 0) *accum = 0.0;
    se[k] = np_sum256_sq(emb + (size_t)k * DD);
}

// ---------- split emb -> dc-tiled bf16 hi/lo planes: plane[tile][k][32] ----------
__global__ void vq_split(const float* __restrict__ emb,
                         unsigned short* __restrict__ ph,
                         unsigned short* __restrict__ pl) {
    int f = (blockIdx.x * 256 + threadIdx.x) * 4;   // element index
    float4 v = *reinterpret_cast<const float4*>(emb + f);
    int k = f >> 8, d = f & 255;
    int off = (d >> 5) * (KC * DK) + k * DK + (d & 31);
    unsigned p0 = cvt_split(v.x), p1 = cvt_split(v.y);
    unsigned p2 = cvt_split(v.z), p3 = cvt_split(v.w);
    us4 h, l;
    h[0] = (unsigned short)(p0 >> 16); l[0] = (unsigned short)p0;
    h[1] = (unsigned short)(p1 >> 16); l[1] = (unsigned short)p1;
    h[2] = (unsigned short)(p2 >> 16); l[2] = (unsigned short)p2;
    h[3] = (unsigned short)(p3 >> 16); l[3] = (unsigned short)p3;
    *reinterpret_cast<us4*>(ph + off) = h;
    *reinterpret_cast<us4*>(pl + off) = l;
}

// ---------- main: per-block 64 rows x 256 codes, bf16-split MFMA ----------
__global__ __launch_bounds__(256, 3)
void vq_main(const float* __restrict__ ze, const float* __restrict__ emb,
             const unsigned short* __restrict__ ph, const unsigned short* __restrict__ pl,
             const float* __restrict__ se_g, float* __restrict__ out_zq,
             float* __restrict__ out_inds, double* __restrict__ accum)
{
    __shared__ __attribute__((aligned(16))) unsigned short zs_hi[BM * SW];
    __shared__ __attribute__((aligned(16))) unsigned short zs_lo[BM * SW];
    __shared__ __attribute__((aligned(16))) unsigned short es_hi[KC * SW];  // epilogue: wv1/wv2/wk1
    __shared__ __attribute__((aligned(16))) unsigned short es_lo[KC * SW];  // epilogue: red/rk2/zfull/srow
    __shared__ float  se_s[KC];
    __shared__ int    inds_s[BM];
    __shared__ int    flist[BM];
    __shared__ int    nflag;

    // epilogue aliases (es dead after post-loop barrier)
    float* wv1 = reinterpret_cast<float*>(es_hi);            // [4*BM]
    float* wv2 = wv1 + 4 * BM;                               // [4*BM]
    int*   wk1 = reinterpret_cast<int*>(wv2 + 4 * BM);       // [4*BM]
    float* red   = reinterpret_cast<float*>(es_lo);          // [256]
    int*   rk2   = reinterpret_cast<int*>(red + 256);        // [256]
    float* zfull = reinterpret_cast<float*>(rk2 + 256);      // [256]
    float* srow  = zfull + 256;                              // [1]

    const int t = threadIdx.x;
    const int w = t >> 6;          // wave: cols [64w, 64w+64)
    const int l = t & 63;
    const int q = (t >> 4) & 3;    // lane quad
    const int c = t & 15;
    const size_t m0 = (size_t)blockIdx.x * BM;

    se_s[t] = se_g[t];
    if (t == 0) nflag = 0;

    f32x4 acc[4][4];
#pragma unroll
    for (int i = 0; i < 4; ++i)
#pragma unroll
        for (int j = 0; j < 4; ++j) acc[i][j] = (f32x4){0.f, 0.f, 0.f, 0.f};
    float sz_acc = 0.f;

    for (int dc = 0; dc < DD; dc += DK) {
        __syncthreads();
        // ---- stage e tile: pure copy from pre-split tiled planes (16B coalesced) ----
        const unsigned short* ehp = ph + (dc >> 5) * (KC * DK);
        const unsigned short* elp = pl + (dc >> 5) * (KC * DK);
#pragma unroll
        for (int it = 0; it < 4; ++it) {
            int idx = it * 256 + t;
            int row = idx >> 2, c8 = idx & 3;
            us8 h = *reinterpret_cast<const us8*>(ehp + idx * 8);
            us8 lo = *reinterpret_cast<const us8*>(elp + idx * 8);
            *reinterpret_cast<us8*>(&es_hi[row * SW + c8 * 8]) = h;
            *reinterpret_cast<us8*>(&es_lo[row * SW + c8 * 8]) = lo;
        }
        // ---- stage z tile: 64 rows x 32 d, fp32 -> bf16 hi/lo inline ----
#pragma unroll
        for (int it = 0; it < 2; ++it) {
            int idx = it * 256 + t;
            int row = idx >> 3, c4 = idx & 7;
            float4 v = *reinterpret_cast<const float4*>(ze + (m0 + row) * DD + dc + c4 * 4);
            sz_acc = fmaf(v.x, v.x, sz_acc); sz_acc = fmaf(v.y, v.y, sz_acc);
            sz_acc = fmaf(v.z, v.z, sz_acc); sz_acc = fmaf(v.w, v.w, sz_acc);
            unsigned p0 = cvt_split(v.x), p1 = cvt_split(v.y);
            unsigned p2 = cvt_split(v.z), p3 = cvt_split(v.w);
            us4 h, lo;
            h[0] = (unsigned short)(p0 >> 16); lo[0] = (unsigned short)p0;
            h[1] = (unsigned short)(p1 >> 16); lo[1] = (unsigned short)p1;
            h[2] = (unsigned short)(p2 >> 16); lo[2] = (unsigned short)p2;
            h[3] = (unsigned short)(p3 >> 16); lo[3] = (unsigned short)p3;
            *reinterpret_cast<us4*>(&zs_hi[row * SW + c4 * 4]) = h;
            *reinterpret_cast<us4*>(&zs_lo[row * SW + c4 * 4]) = lo;
        }
        __syncthreads();
        // ---- MFMA: wave tile 64 rows x 64 cols, 4x4 frags, 3 passes ----
        bf16x8 a_hi[4], a_lo[4], b_hi[4], b_lo[4];
#pragma unroll
        for (int mf = 0; mf < 4; ++mf) {
            a_hi[mf] = *reinterpret_cast<const bf16x8*>(&zs_hi[(16 * mf + c) * SW + q * 8]);
            a_lo[mf] = *reinterpret_cast<const bf16x8*>(&zs_lo[(16 * mf + c) * SW + q * 8]);
        }
#pragma unroll
        for (int nf = 0; nf < 4; ++nf) {
            b_hi[nf] = *reinterpret_cast<const bf16x8*>(&es_hi[(64 * w + 16 * nf + c) * SW + q * 8]);
            b_lo[nf] = *reinterpret_cast<const bf16x8*>(&es_lo[(64 * w + 16 * nf + c) * SW + q * 8]);
        }
#pragma unroll
        for (int mf = 0; mf < 4; ++mf)
#pragma unroll
            for (int nf = 0; nf < 4; ++nf) {
                acc[mf][nf] = __builtin_amdgcn_mfma_f32_16x16x32_bf16(a_lo[mf], b_hi[nf], acc[mf][nf], 0, 0, 0);
                acc[mf][nf] = __builtin_amdgcn_mfma_f32_16x16x32_bf16(a_hi[mf], b_lo[nf], acc[mf][nf], 0, 0, 0);
                acc[mf][nf] = __builtin_amdgcn_mfma_f32_16x16x32_bf16(a_hi[mf], b_hi[nf], acc[mf][nf], 0, 0, 0);
            }
    }
    __syncthreads();   // es region now dead -> safe for epilogue aliases

    // ---- per-row argmin over this wave's 64-col slice (v1, v2, k1) ----
#pragma unroll
    for (int mf = 0; mf < 4; ++mf)
#pragma unroll
        for (int j = 0; j < 4; ++j) {
            float v1 = 3.4e38f, v2 = 3.4e38f; int k1 = 0x7fffffff;
#pragma unroll
            for (int nf = 0; nf < 4; ++nf) {
                int k = 64 * w + 16 * nf + c;
                float dv = fmaf(-2.f, acc[mf][nf][j], se_s[k]);
                if (dv < v1) { v2 = v1; v1 = dv; k1 = k; }
                else if (dv < v2) { v2 = dv; }
            }
#pragma unroll
            for (int off = 1; off < 16; off <<= 1) {
                float ov1 = __shfl_xor(v1, off, 64);
                float ov2 = __shfl_xor(v2, off, 64);
                int   ok1 = __shfl_xor(k1, off, 64);
                bool other = (ov1 < v1) || (ov1 == v1 && ok1 < k1);
                float nv2 = other ? fminf(v1, ov2) : fminf(v2, ov1);
                if (other) { v1 = ov1; k1 = ok1; }
                v2 = nv2;
            }
            if (c == 0) {
                int row = 16 * mf + 4 * q + j;
                wv1[w * BM + row] = v1; wv2[w * BM + row] = v2; wk1[w * BM + row] = k1;
            }
        }
    __syncthreads();

    // ---- cross-wave merge (t < 64: one row each), flag near-ties ----
    float lossv = 0.f;
    if (t < BM) {
        float v1 = wv1[t], v2 = wv2[t]; int k1 = wk1[t];
#pragma unroll
        for (int ww = 1; ww < 4; ++ww) {
            float ov1 = wv1[ww * BM + t], ov2 = wv2[ww * BM + t];
            int ok1 = wk1[ww * BM + t];
            bool other = (ov1 < v1) || (ov1 == v1 && ok1 < k1);
            float nv2 = other ? fminf(v1, ov2) : fminf(v2, ov1);
            if (other) { v1 = ov1; k1 = ok1; }
            v2 = nv2;
        }
        inds_s[t] = k1;
        lossv = v1;
        if (v2 - v1 < TAU) {
            int s = atomicAdd(&nflag, 1);
            flist[s] = t;
        }
    }
    __syncthreads();

    // ---- flagged rows: BIT-EXACT numpy fp32 pipeline emulation (proven r3) ----
    int nf = nflag;
    for (int f = 0; f < nf; ++f) {
        int row = flist[f];
        if (t < 64)
            reinterpret_cast<float4*>(zfull)[t] =
                reinterpret_cast<const float4*>(ze + (m0 + row) * DD)[t];
        __syncthreads();
        if (t == 0) *srow = np_sum256_sq(zfull);
        __syncthreads();
        const float4* e4p = reinterpret_cast<const float4*>(emb + (size_t)t * DD);
        float m32 = 0.f;
        for (int d4 = 0; d4 < 64; ++d4) {
            float4 e4 = e4p[d4];
            int d = d4 * 4;
            m32 = __fmaf_rn(zfull[d + 0], e4.x, m32);
            m32 = __fmaf_rn(zfull[d + 1], e4.y, m32);
            m32 = __fmaf_rn(zfull[d + 2], e4.z, m32);
            m32 = __fmaf_rn(zfull[d + 3], e4.w, m32);
        }
        float A  = __fadd_rn(*srow, se_s[t]);
        float Dq = __fsub_rn(A, __fmul_rn(2.0f, m32));
        red[t] = Dq; rk2[t] = t;
        __syncthreads();
        for (int s = 128; s > 0; s >>= 1) {
            if (t < s) {
                float vo = red[t + s]; int ko = rk2[t + s];
                if (vo < red[t] || (vo == red[t] && ko < rk2[t])) { red[t] = vo; rk2[t] = ko; }
            }
            __syncthreads();
        }
        if (t == 0) inds_s[row] = rk2[0];
        __syncthreads();
    }

    // ---- write indices (as float) ----
    if (t < BM) out_inds[m0 + t] = (float)inds_s[t];

    // ---- gather + write z_q (wave per row, lane per float4) ----
    for (int r = w; r < BM; r += 4) {
        int k = inds_s[r];
        float4 v = *reinterpret_cast<const float4*>(emb + (size_t)k * DD + l * 4);
        *reinterpret_cast<float4*>(out_zq + (m0 + r) * DD + l * 4) = v;
    }

    // ---- loss partial ----
    red[t] = sz_acc + lossv;
    __syncthreads();
    for (int s = 128; s > 0; s >>= 1) {
        if (t < s) red[t] += red[t + s];
        __syncthreads();
    }
    if (t == 0) atomicAdd(accum, (double)red[0]);
}

// ---------- finalize: loss = (1 + 0.25) * mean((z - q)^2) ----------
__global__ void vq_fin(const double* __restrict__ accum, float* __restrict__ out_loss) {
    *out_loss = (float)(1.25 * (*accum) / ((double)NROWS * (double)DD));
}

extern "C" void kernel_launch(void* const* d_in, const int* in_sizes, int n_in,
                              void* d_out, int out_size, void* d_ws, size_t ws_size,
                              hipStream_t stream) {
    const float* ze  = (const float*)d_in[0];
    const float* emb = (const float*)d_in[1];
    float* out      = (float*)d_out;
    float* out_zq   = out;
    float* out_inds = out + (size_t)NROWS * DD;
    float* out_loss = out + (size_t)NROWS * DD + NROWS;
    double* accum = (double*)d_ws;
    float*  se    = (float*)((char*)d_ws + 16);
    unsigned short* ph = (unsigned short*)((char*)d_ws + 2048);            // 128 KB
    unsigned short* pl = (unsigned short*)((char*)d_ws + 2048 + 131072);   // 128 KB

    vq_prep<<<1, 256, 0, stream>>>(emb, se, accum);
    vq_split<<<KC * DD / (256 * 4), 256, 0, stream>>>(emb, ph, pl);
    vq_main<<<NROWS / BM, 256, 0, stream>>>(ze, emb, ph, pl, se, out_zq, out_inds, accum);
    vq_fin<<<1, 1, 0, stream>>>(accum, out_loss);
}